// Round 5
// baseline (3437.374 us; speedup 1.0000x reference)
//
#include <hip/hip_runtime.h>
#include <math.h>

// Problem constants (4, 19, 512, 512) fp32
#define BB 4
#define CC 19
#define HH 512
#define WW 512
#define NSLICE (BB * CC)        // 76
#define SLICE  (HH * WW)        // 262144
#define W4     (WW / 4)         // 128 float4 per row
#define EPS    1e-12f
#define NEGINF (-INFINITY)

// time-tiling params
#define TSTEPS 16
#define RROWS  64
#define AROWS  96               // RROWS + 2*TSTEPS
#define NPASS  16               // 256 / TSTEPS
#define RBLK   8                // HH / RROWS

// thread geometry: 64 lanes across (8 cols each) x 16 waves (6 rows each)
#define TX   64
#define TY   16
#define COLS 8
#define ROWS 6

struct F8 { float4 a, b; };

// ---------------------------------------------------------------------------
__global__ void init_kernel(const float* __restrict__ x, float* __restrict__ cur) {
    int t = blockIdx.x * blockDim.x + threadIdx.x;
    const float4* x4 = (const float4*)x;
    float4* c4 = (float4*)cur;
    float4 v = x4[t];
    int pix = t << 2;
    int s = pix & (SLICE - 1);
    int i = s >> 9;
    int j0 = s & 511;
    float4 o;
    o.x = -v.x; o.y = -v.y; o.z = -v.z; o.w = -v.w;
    if (i == 0 || i == HH - 1) {
        o.x = 1.0f; o.y = 1.0f; o.z = 1.0f; o.w = 1.0f;
    } else {
        if (j0 == 0)        o.x = 1.0f;
        if (j0 == WW - 4)   o.w = 1.0f;
    }
    c4[t] = o;
}

// ---------------------------------------------------------------------------
// one pass = TSTEPS fused (maxpool3x3 * x) steps on a 512x96 tile.
// 1024 threads: wave = one 6-row strip spanning the full 512 cols; thread =
// 8 cols x 6 rows register patch (96 array floats/thread -> fits the forced
// 128-VGPR budget of a 16-wave block; R4's 512-thr version needed 192 and
// shuttled half through AGPRs -> 3x VALU overhead + 8 waves/CU).
// Horizontal 3-max: 2 in-wave shuffles/row. Vertical cross-wave halo: LDS,
// component-major [ty][8][tx] (2-way bank alias = free). Trapezoid skip:
// strip computes iteration t only while its rows can still reach valid
// output (wave-uniform; pre-step snapshot semantics make this exact).
__global__ __launch_bounds__(1024, 1)
void pass_kernel(const float* __restrict__ in, const float* __restrict__ xg,
                 float* __restrict__ out) {
    const int tid  = threadIdx.x;
    const int tx   = tid & 63;          // lane = column group
    const int ty   = tid >> 6;          // wave = thread-row strip
    const int bc   = blockIdx.x / RBLK;
    const int brow = blockIdx.x % RBLK;
    const int gstart = brow * RROWS - TSTEPS;       // tile row a=0 -> global row
    const int row0   = gstart + ty * ROWS;          // this thread's r=0 global row
    const int col0   = tx * COLS;
    const size_t sbase = (size_t)bc * SLICE;

    __shared__ float Tb[TY][8][TX];     // top-row snapshot of each strip
    __shared__ float Bb[TY][8][TX];     // bottom-row snapshot of each strip

    const float4 neg4 = make_float4(NEGINF, NEGINF, NEGINF, NEGINF);
    const float4 one4 = make_float4(1.f, 1.f, 1.f, 1.f);

    float4 cl[ROWS], cr[ROWS], xl[ROWS], xr_[ROWS];

#pragma unroll
    for (int r = 0; r < ROWS; ++r) {
        int grow = row0 + r;
        if (grow >= 0 && grow < HH) {               // wave-uniform branch
            const float4* p = (const float4*)(in + sbase + (size_t)grow * WW + col0);
            cl[r] = p[0]; cr[r] = p[1];
            const float4* q = (const float4*)(xg + sbase + (size_t)grow * WW + col0);
            xl[r] = q[0]; xr_[r] = q[1];
        } else {
            cl[r] = neg4; cr[r] = neg4; xl[r] = one4; xr_[r] = one4;
        }
    }

    // horizontal 3-max of one 8-px row
    auto hrow = [&](float4 a, float4 b) -> F8 {
        float lpx = __shfl_up(b.w, 1);
        float rpx = __shfl_down(a.x, 1);
        if (tx == 0)  lpx = NEGINF;
        if (tx == 63) rpx = NEGINF;
        F8 h;
        h.a.x = fmaxf(fmaxf(lpx, a.x), a.y);
        h.a.y = fmaxf(fmaxf(a.x, a.y), a.z);
        h.a.z = fmaxf(fmaxf(a.y, a.z), a.w);
        h.a.w = fmaxf(fmaxf(a.z, a.w), b.x);
        h.b.x = fmaxf(fmaxf(a.w, b.x), b.y);
        h.b.y = fmaxf(fmaxf(b.x, b.y), b.z);
        h.b.z = fmaxf(fmaxf(b.y, b.z), b.w);
        h.b.w = fmaxf(fmaxf(b.z, b.w), rpx);
        return h;
    };

    const int amin = ty * ROWS;
    const int amax = amin + ROWS - 1;

    for (int t = 0; t < TSTEPS; ++t) {
        // snapshot pre-step top/bottom rows (unconditional: stale rows of
        // skipped strips are exactly the post-last-active-step values the
        // neighbor needs)
        Tb[ty][0][tx] = cl[0].x; Tb[ty][1][tx] = cl[0].y;
        Tb[ty][2][tx] = cl[0].z; Tb[ty][3][tx] = cl[0].w;
        Tb[ty][4][tx] = cr[0].x; Tb[ty][5][tx] = cr[0].y;
        Tb[ty][6][tx] = cr[0].z; Tb[ty][7][tx] = cr[0].w;
        Bb[ty][0][tx] = cl[ROWS-1].x; Bb[ty][1][tx] = cl[ROWS-1].y;
        Bb[ty][2][tx] = cl[ROWS-1].z; Bb[ty][3][tx] = cl[ROWS-1].w;
        Bb[ty][4][tx] = cr[ROWS-1].x; Bb[ty][5][tx] = cr[ROWS-1].y;
        Bb[ty][6][tx] = cr[ROWS-1].z; Bb[ty][7][tx] = cr[ROWS-1].w;
        __syncthreads();

        // trapezoid skip: rows a needed post-step-(t+1) iff t+1 <= a <= 94-t
        if (amax >= t + 1 && amin <= 94 - t) {      // wave-uniform
            float4 upA, upB, dnA, dnB;
            if (ty > 0) {
                upA = make_float4(Bb[ty-1][0][tx], Bb[ty-1][1][tx],
                                  Bb[ty-1][2][tx], Bb[ty-1][3][tx]);
                upB = make_float4(Bb[ty-1][4][tx], Bb[ty-1][5][tx],
                                  Bb[ty-1][6][tx], Bb[ty-1][7][tx]);
            } else { upA = neg4; upB = neg4; }
            if (ty < TY - 1) {
                dnA = make_float4(Tb[ty+1][0][tx], Tb[ty+1][1][tx],
                                  Tb[ty+1][2][tx], Tb[ty+1][3][tx]);
                dnB = make_float4(Tb[ty+1][4][tx], Tb[ty+1][5][tx],
                                  Tb[ty+1][6][tx], Tb[ty+1][7][tx]);
            } else { dnA = neg4; dnB = neg4; }

            F8 hA = hrow(upA, upB);
            F8 hB = hrow(cl[0], cr[0]);
#pragma unroll
            for (int r = 0; r < ROWS; ++r) {
                F8 hC;
                if (r + 1 < ROWS) hC = hrow(cl[r + 1], cr[r + 1]);
                else              hC = hrow(dnA, dnB);
                float4 vl, vr;
                vl.x = fmaxf(fmaxf(hA.a.x, hB.a.x), hC.a.x);
                vl.y = fmaxf(fmaxf(hA.a.y, hB.a.y), hC.a.y);
                vl.z = fmaxf(fmaxf(hA.a.z, hB.a.z), hC.a.z);
                vl.w = fmaxf(fmaxf(hA.a.w, hB.a.w), hC.a.w);
                vr.x = fmaxf(fmaxf(hA.b.x, hB.b.x), hC.b.x);
                vr.y = fmaxf(fmaxf(hA.b.y, hB.b.y), hC.b.y);
                vr.z = fmaxf(fmaxf(hA.b.z, hB.b.z), hC.b.z);
                vr.w = fmaxf(fmaxf(hA.b.w, hB.b.w), hC.b.w);
                cl[r].x = vl.x * xl[r].x;  cl[r].y = vl.y * xl[r].y;
                cl[r].z = vl.z * xl[r].z;  cl[r].w = vl.w * xl[r].w;
                cr[r].x = vr.x * xr_[r].x; cr[r].y = vr.y * xr_[r].y;
                cr[r].z = vr.z * xr_[r].z; cr[r].w = vr.w * xr_[r].w;
                hA = hB; hB = hC;
            }
            // rows outside the image stay -inf (maxpool pad semantics)
#pragma unroll
            for (int r = 0; r < ROWS; ++r) {
                int grow = row0 + r;
                if (grow < 0 || grow >= HH) { cl[r] = neg4; cr[r] = neg4; }
            }
        }
        __syncthreads();                 // protect snapshots until reads done
    }

    // store valid center rows: tile rows a in [TSTEPS, TSTEPS+RROWS)
#pragma unroll
    for (int r = 0; r < ROWS; ++r) {
        int a = amin + r;                // wave-uniform condition
        if (a >= TSTEPS && a < TSTEPS + RROWS) {
            int grow = row0 + r;
            float4* p = (float4*)(out + sbase + (size_t)grow * WW + col0);
            p[0] = cl[r]; p[1] = cr[r];
        }
    }
}

// ---------------------------------------------------------------------------
// final: norm over channel dim (19), out = cur * x / max(||cur||_2, eps)
__global__ void norm_kernel(const float* __restrict__ cur,
                            const float* __restrict__ x,
                            float* __restrict__ out) {
    int t = blockIdx.x * blockDim.x + threadIdx.x;
    int j4 = t & (W4 - 1);
    int i  = (t >> 7) & (HH - 1);
    int b  = t >> 16;
    size_t off = (size_t)b * CC * SLICE + (size_t)i * WW + (j4 << 2);

    float4 vals[CC];
    float sx = 0.f, sy = 0.f, sz = 0.f, sw = 0.f;
#pragma unroll
    for (int c = 0; c < CC; ++c) {
        float4 v = *(const float4*)(cur + off + (size_t)c * SLICE);
        vals[c] = v;
        sx += v.x * v.x; sy += v.y * v.y; sz += v.z * v.z; sw += v.w * v.w;
    }
    float4 r;
    r.x = 1.0f / fmaxf(sqrtf(sx), EPS);
    r.y = 1.0f / fmaxf(sqrtf(sy), EPS);
    r.z = 1.0f / fmaxf(sqrtf(sz), EPS);
    r.w = 1.0f / fmaxf(sqrtf(sw), EPS);
#pragma unroll
    for (int c = 0; c < CC; ++c) {
        float4 xv = *(const float4*)(x + off + (size_t)c * SLICE);
        float4 o;
        o.x = vals[c].x * xv.x * r.x;
        o.y = vals[c].y * xv.y * r.y;
        o.z = vals[c].z * xv.z * r.z;
        o.w = vals[c].w * xv.w * r.w;
        *(float4*)(out + off + (size_t)c * SLICE) = o;
    }
}

// ---------------------------------------------------------------------------
extern "C" void kernel_launch(void* const* d_in, const int* in_sizes, int n_in,
                              void* d_out, int out_size, void* d_ws, size_t ws_size,
                              hipStream_t stream) {
    const float* x = (const float*)d_in[0];
    float* out = (float*)d_out;
    float* ws  = (float*)d_ws;        // >= 79,691,776 B

    const int initBlocks = NSLICE * SLICE / 4 / 256; // 19456
    const int passBlocks = NSLICE * RBLK;            // 608
    const int normBlocks = BB * HH * W4 / 256;       // 1024

    init_kernel<<<initBlocks, 256, 0, stream>>>(x, ws);
    float* a = ws;
    float* b = out;
    for (int it = 0; it < NPASS; ++it) {
        pass_kernel<<<passBlocks, 1024, 0, stream>>>(a, x, b);
        float* tmp = a; a = b; b = tmp;
    }
    // NPASS even -> result back in ws
    norm_kernel<<<normBlocks, 256, 0, stream>>>(ws, x, out);
}